// Round 15
// baseline (714.773 us; speedup 1.0000x reference)
//
#include <hip/hip_runtime.h>

typedef unsigned short u16;
using u16x8  = __attribute__((ext_vector_type(8))) unsigned short;
using bf16x8 = __attribute__((ext_vector_type(8))) __bf16;
using f32x4  = __attribute__((ext_vector_type(4))) float;

#define NKVAL 32768
#define NQVAL 262144
#define EVAL  524288

__device__ __forceinline__ u16 f2bf(float f) {
  unsigned u = __float_as_uint(f);
  u = (u + 0x7fffu + ((u >> 16) & 1u)) >> 16;   // RNE
  return (u16)u;
}
__device__ __forceinline__ float bf2f(u16 h) {
  return __uint_as_float(((unsigned)h) << 16);
}
__device__ __forceinline__ void gl2lds16(const u16* g, u16* l) {
  __builtin_amdgcn_global_load_lds((const __attribute__((address_space(1))) void*)g,
                                   (__attribute__((address_space(3))) void*)l, 16, 0, 0);
}

// ---------------- int degree ----------------
__global__ __launch_bounds__(256) void degcnt_k(const int* __restrict__ dst, int* __restrict__ cnt) {
  int e = blockIdx.x * 256 + threadIdx.x;
  if (e < EVAL) atomicAdd(&cnt[dst[e]], 1);
}

// ---------------- exclusive scan over cnt[NKVAL] -> off[NKVAL+1], single block ----------------
__global__ __launch_bounds__(1024) void scan_k(const int* __restrict__ cnt, int* __restrict__ off) {
  __shared__ int part[1024];
  const int t = threadIdx.x;
  const int base = t * 32;
  int local[32];
  int s = 0;
#pragma unroll
  for (int i = 0; i < 32; i++) { local[i] = s; s += cnt[base + i]; }
  part[t] = s;
  __syncthreads();
  for (int d = 1; d < 1024; d <<= 1) {
    int v = (t >= d) ? part[t - d] : 0;
    __syncthreads();
    part[t] += v;
    __syncthreads();
  }
  int pre = (t == 0) ? 0 : part[t - 1];
#pragma unroll
  for (int i = 0; i < 32; i++) off[base + i] = pre + local[i];
  if (t == 1023) off[NKVAL] = pre + s;
}

// ---------------- scatter edges into CSR-by-dst ----------------
__global__ __launch_bounds__(256) void scatter_k(const int* __restrict__ src, const int* __restrict__ dst,
                                                 const int* __restrict__ off, int* __restrict__ cur,
                                                 int* __restrict__ srcs_sorted) {
  int e = blockIdx.x * 256 + threadIdx.x;
  if (e < EVAL) {
    int d = dst[e];
    int p = atomicAdd(&cur[d], 1);
    srcs_sorted[off[d] + p] = src[e];
  }
}

// ---------------- layer-0 aggregation via CSR (no atomics) ----------------
__global__ __launch_bounds__(256) void agg0_csr(const int* __restrict__ off, const int* __restrict__ srcs,
                                                const float* __restrict__ known, float* __restrict__ m0) {
  int d = blockIdx.x * 256 + threadIdx.x;
  if (d >= NKVAL) return;
  int b = off[d], e = off[d + 1];
  float a0 = 0.f, a1 = 0.f, a2 = 0.f;
  for (int i = b; i < e; i++) {
    int s = srcs[i];
    a0 += known[s * 3 + 0];
    a1 += known[s * 3 + 1];
    a2 += known[s * 3 + 2];
  }
  m0[d * 3 + 0] = a0;
  m0[d * 3 + 1] = a1;
  m0[d * 3 + 2] = a2;
}

// ---------------- K=3 dense: Y = relu((X[/cnt]) @ W[3,512] + b) -> bf16, vectorized ----------------
__global__ __launch_bounds__(256) void k3_dense(const float* __restrict__ X, const int* __restrict__ cnt,
                                                const float* __restrict__ W, const float* __restrict__ Bb,
                                                u16* __restrict__ Y, int M) {
  int id = blockIdx.x * 256 + threadIdx.x;  // M*64 threads, 8 outputs each
  if (id >= M * 64) return;
  int i = id >> 6, j0 = (id & 63) * 8;
  float x0 = X[i * 3 + 0], x1 = X[i * 3 + 1], x2 = X[i * 3 + 2];
  if (cnt) {
    float inv = 1.0f / fmaxf((float)cnt[i], 1.0f);
    x0 *= inv; x1 *= inv; x2 *= inv;
  }
  u16x8 o;
#pragma unroll
  for (int j = 0; j < 8; j++) {
    float v = fmaf(x0, W[j0 + j], Bb[j0 + j]);
    v = fmaf(x1, W[512 + j0 + j], v);
    v = fmaf(x2, W[1024 + j0 + j], v);
    o[j] = f2bf(fmaxf(v, 0.0f));
  }
  *(u16x8*)(Y + (size_t)i * 512 + j0) = o;
}

// ---------------- GCN aggregation via CSR: wave per dst node, regs only ----------------
__global__ __launch_bounds__(256) void agg_csr(const u16* __restrict__ H, const int* __restrict__ off,
                                               const int* __restrict__ srcs, u16* __restrict__ Mo) {
  const int raw = blockIdx.x;
  const int nb = (raw & 7) * 1024 + (raw >> 3);
  const int node = nb * 4 + (threadIdx.x >> 6);
  const int lane = threadIdx.x & 63;
  const int beg = off[node], end = off[node + 1];
  const int c0 = lane * 8;
  float acc[8] = {0, 0, 0, 0, 0, 0, 0, 0};
  int e = beg;
  for (; e + 4 <= end; e += 4) {
    int s0 = srcs[e], s1 = srcs[e + 1], s2 = srcs[e + 2], s3 = srcs[e + 3];
    u16x8 h0 = *(const u16x8*)(H + (size_t)s0 * 512 + c0);
    u16x8 h1 = *(const u16x8*)(H + (size_t)s1 * 512 + c0);
    u16x8 h2 = *(const u16x8*)(H + (size_t)s2 * 512 + c0);
    u16x8 h3 = *(const u16x8*)(H + (size_t)s3 * 512 + c0);
#pragma unroll
    for (int j = 0; j < 8; j++)
      acc[j] += (bf2f(h0[j]) + bf2f(h1[j])) + (bf2f(h2[j]) + bf2f(h3[j]));
  }
  for (; e < end; e++) {
    int s = srcs[e];
    u16x8 hv = *(const u16x8*)(H + (size_t)s * 512 + c0);
#pragma unroll
    for (int j = 0; j < 8; j++) acc[j] += bf2f(hv[j]);
  }
  float inv = 1.0f / fmaxf((float)(end - beg), 1.0f);
  u16x8 o;
#pragma unroll
  for (int j = 0; j < 8; j++) o[j] = f2bf(acc[j] * inv);
  *(u16x8*)(Mo + (size_t)node * 512 + c0) = o;
}

// ---------------- weight cast+transpose x4 in one launch: WT[n][k] = bf16(W[k][n]) ----------------
__global__ __launch_bounds__(256) void wcast4_k(const float* __restrict__ s0, const float* __restrict__ s1,
                                                const float* __restrict__ s2, const float* __restrict__ s3,
                                                u16* __restrict__ d0, u16* __restrict__ d1,
                                                u16* __restrict__ d2, u16* __restrict__ d3) {
  const float* W = (blockIdx.z == 0) ? s0 : (blockIdx.z == 1) ? s1 : (blockIdx.z == 2) ? s2 : s3;
  u16* WT = (blockIdx.z == 0) ? d0 : (blockIdx.z == 1) ? d1 : (blockIdx.z == 2) ? d2 : d3;
  __shared__ u16 tile[64][72];
  const int k0 = blockIdx.y * 64, n0 = blockIdx.x * 64, t = threadIdx.x;
#pragma unroll
  for (int i = 0; i < 16; i++) {
    int kk = (t >> 6) * 16 + i, nn = t & 63;
    tile[nn][kk] = f2bf(W[(size_t)(k0 + kk) * 512 + n0 + nn]);
  }
  __syncthreads();
#pragma unroll
  for (int i = 0; i < 16; i++) {
    int nn = (t >> 6) * 16 + i, kk = t & 63;
    WT[(size_t)(n0 + nn) * 512 + k0 + kk] = tile[nn][kk];
  }
}

// ---------------- pooling ----------------
__global__ __launch_bounds__(256) void pool_k(const u16* __restrict__ H2, float* __restrict__ pooled) {
  __shared__ float red[256][8];
  const int g = blockIdx.y, chunk = blockIdx.x, t = threadIdx.x;
  const int cg = t & 63, rs = t >> 6;
  const int r0 = chunk * 128;
  float a[8] = {0, 0, 0, 0, 0, 0, 0, 0};
  for (int r = r0 + rs; r < r0 + 128; r += 4) {
    u16x8 v = *(const u16x8*)(H2 + ((size_t)(g << 10) + r) * 512 + cg * 8);
#pragma unroll
    for (int j = 0; j < 8; j++) a[j] += bf2f(v[j]);
  }
#pragma unroll
  for (int j = 0; j < 8; j++) red[t][j] = a[j];
  __syncthreads();
  if (t < 64) {
#pragma unroll
    for (int j = 0; j < 8; j++) {
      float s = red[t][j] + red[t + 64][j] + red[t + 128][j] + red[t + 192][j];
      atomicAdd(&pooled[g * 512 + t * 8 + j], s * (1.0f / 1024.0f));
    }
  }
}

// ---------------- field = pooled @ gc_wr + gc_br ----------------
__global__ __launch_bounds__(256) void field_k(const float* __restrict__ pooled, const float* __restrict__ wr,
                                               const float* __restrict__ br, float* __restrict__ field) {
  int id = blockIdx.x * 256 + threadIdx.x;  // 32*512
  int g = id >> 9, j = id & 511;
  float s = br[j];
  for (int k = 0; k < 512; k++) s = fmaf(pooled[g * 512 + k], wr[k * 512 + j], s);
  field[id] = s;
}

// ---------------- final reduce: out = sum of 8 partial slices + bo2 ----------------
__global__ __launch_bounds__(256) void out_reduce(const float* __restrict__ part, const float* __restrict__ bo2,
                                                  float* __restrict__ out) {
  int id = blockIdx.x * 256 + threadIdx.x;  // NQ*3
  float s = bo2[id % 3];
#pragma unroll
  for (int sl = 0; sl < 8; sl++) s += part[(size_t)sl * NQVAL * 3 + id];
  out[id] = s;
}

// ---------------- GEMM: C = epilogue(A[M,512] @ BT[512,512]^T + bias) ----------------
// 256x256 tile, 8 waves (512 thr, 2x4 wave grid, 128x64 out each), BK=32,
// 4-buffer LDS (128KB), depth-3 prefetch, counted vmcnt; XOR swizzle (r7 verified, 998 TF).
// MODE 0: A from memory; C = relu(.) -> bf16            (GCN hidden layers)
// MODE 1: A = relu(nodes@wt1+bt1) computed in staging;  C = (.) * field[row>>13]
// MODE 2: A from memory; partial[slice] = relu(.) @ wo2 (no atomics)
template <int MODE>
__global__ __launch_bounds__(512) void gemm_bt(const u16* __restrict__ A, const u16* __restrict__ BT,
                                               const float* __restrict__ bias, const float* __restrict__ field,
                                               const float* __restrict__ wo2, u16* __restrict__ C,
                                               float* __restrict__ outp, long rowoff,
                                               const float* __restrict__ nodes3,
                                               const float* __restrict__ wt1,
                                               const float* __restrict__ bt1) {
  constexpr int K = 512;
  constexpr int NT = 16;  // K / 32
  __shared__ u16 As[4][256 * 32];
  __shared__ u16 Bs[4][256 * 32];
  const int t = threadIdx.x;
  const int wave = t >> 6, lane = t & 63;
  const int wr = wave >> 2, wc = wave & 3;   // 2x4 wave grid, 128x64 out each
  const int lr = lane & 15, kg = lane >> 4;  // frag row, k-group
  const int kx = (lr >> 1) & 3;              // read-side slot XOR key
  const long bm0 = (long)blockIdx.y * 256;
  const int bn0 = blockIdx.x * 256;
  f32x4 acc[8][4] = {};
  const int arow = t >> 2;
  const int acs = (((t & 3) ^ ((t >> 3) & 3)) * 8);
  const u16* gA0 = nullptr;
  const u16* gA1 = nullptr;
  if constexpr (MODE != 1) {
    gA0 = A + (bm0 + arow) * K + acs;
    gA1 = gA0 + 128 * K;
  }
  const u16* gB0 = BT + (long)(bn0 + arow) * K + acs;
  const u16* gB1 = gB0 + 128 * K;
  float n0x = 0, n0y = 0, n0z = 0, n1x = 0, n1y = 0, n1z = 0;
  if constexpr (MODE == 1) {
    const float* nr0 = nodes3 + (bm0 + arow) * 3;
    const float* nr1 = nodes3 + (bm0 + 128 + arow) * 3;
    n0x = nr0[0]; n0y = nr0[1]; n0z = nr0[2];
    n1x = nr1[0]; n1y = nr1[1]; n1z = nr1[2];
  }

  auto STAGE = [&](int tile) {
    const int b = tile & 3;
    const int kt = tile * 32;
    if constexpr (MODE == 1) {
      float w0[8], w1[8], w2[8], bb[8];
      const float* wp = wt1 + kt + acs;
      *(float4*)&w0[0] = *(const float4*)(wp);
      *(float4*)&w0[4] = *(const float4*)(wp + 4);
      *(float4*)&w1[0] = *(const float4*)(wp + 512);
      *(float4*)&w1[4] = *(const float4*)(wp + 516);
      *(float4*)&w2[0] = *(const float4*)(wp + 1024);
      *(float4*)&w2[4] = *(const float4*)(wp + 1028);
      *(float4*)&bb[0] = *(const float4*)(bt1 + kt + acs);
      *(float4*)&bb[4] = *(const float4*)(bt1 + kt + acs + 4);
      u16x8 o0, o1;
#pragma unroll
      for (int j = 0; j < 8; j++) {
        float v0 = fmaf(n0x, w0[j], fmaf(n0y, w1[j], fmaf(n0z, w2[j], bb[j])));
        float v1 = fmaf(n1x, w0[j], fmaf(n1y, w1[j], fmaf(n1z, w2[j], bb[j])));
        o0[j] = f2bf(fmaxf(v0, 0.0f));
        o1[j] = f2bf(fmaxf(v1, 0.0f));
      }
      *(u16x8*)&As[b][t * 8] = o0;
      *(u16x8*)&As[b][4096 + t * 8] = o1;
    } else {
      gl2lds16(gA0 + kt, &As[b][t * 8]);
      gl2lds16(gA1 + kt, &As[b][4096 + t * 8]);
    }
    gl2lds16(gB0 + kt, &Bs[b][t * 8]);
    gl2lds16(gB1 + kt, &Bs[b][4096 + t * 8]);
  };

  STAGE(0);
  STAGE(1);
  STAGE(2);
  if constexpr (MODE == 1) asm volatile("s_waitcnt vmcnt(4) lgkmcnt(0)" ::: "memory");
  else                     asm volatile("s_waitcnt vmcnt(8)" ::: "memory");
  __builtin_amdgcn_s_barrier();

#pragma unroll
  for (int tt = 0; tt < NT; ++tt) {
    const int b = tt & 3;
    if (tt + 3 < NT) STAGE(tt + 3);
    bf16x8 af[8], bfv[4];
#pragma unroll
    for (int i = 0; i < 8; i++)
      af[i] = *(const bf16x8*)&As[b][(wr * 128 + i * 16 + lr) * 32 + (kg ^ kx) * 8];
#pragma unroll
    for (int n = 0; n < 4; n++)
      bfv[n] = *(const bf16x8*)&Bs[b][(wc * 64 + n * 16 + lr) * 32 + (kg ^ kx) * 8];
#pragma unroll
    for (int i = 0; i < 8; i++)
#pragma unroll
      for (int n = 0; n < 4; n++)
        acc[i][n] = __builtin_amdgcn_mfma_f32_16x16x32_bf16(af[i], bfv[n], acc[i][n], 0, 0, 0);
    if (tt + 1 < NT) {
      const int last_staged = (tt + 3 < NT) ? (tt + 3) : (NT - 1);
      const int ahead = last_staged - (tt + 1);
      if constexpr (MODE == 1) {
        if (ahead >= 2)      asm volatile("s_waitcnt vmcnt(4) lgkmcnt(0)" ::: "memory");
        else if (ahead == 1) asm volatile("s_waitcnt vmcnt(2) lgkmcnt(0)" ::: "memory");
        else                 asm volatile("s_waitcnt vmcnt(0) lgkmcnt(0)" ::: "memory");
      } else {
        if (ahead >= 2)      asm volatile("s_waitcnt vmcnt(8)" ::: "memory");
        else if (ahead == 1) asm volatile("s_waitcnt vmcnt(4)" ::: "memory");
        else                 asm volatile("s_waitcnt vmcnt(0)" ::: "memory");
      }
      __builtin_amdgcn_s_barrier();
    }
  }

  if (MODE == 2) {
    float bb[4], wa[4], wb[4], wv[4];
#pragma unroll
    for (int n = 0; n < 4; n++) {
      int col = bn0 + wc * 64 + n * 16 + lr;
      bb[n] = bias[col];
      wa[n] = wo2[col * 3 + 0];
      wb[n] = wo2[col * 3 + 1];
      wv[n] = wo2[col * 3 + 2];
    }
    const int slice = blockIdx.x * 4 + wc;
#pragma unroll
    for (int i = 0; i < 8; i++) {
      float po[4][3];
#pragma unroll
      for (int r2 = 0; r2 < 4; r2++)
#pragma unroll
        for (int o = 0; o < 3; o++) po[r2][o] = 0.0f;
#pragma unroll
      for (int n = 0; n < 4; n++)
#pragma unroll
        for (int r2 = 0; r2 < 4; r2++) {
          float v = fmaxf(acc[i][n][r2] + bb[n], 0.0f);
          po[r2][0] = fmaf(v, wa[n], po[r2][0]);
          po[r2][1] = fmaf(v, wb[n], po[r2][1]);
          po[r2][2] = fmaf(v, wv[n], po[r2][2]);
        }
#pragma unroll
      for (int s = 1; s < 16; s <<= 1)
#pragma unroll
        for (int r2 = 0; r2 < 4; r2++)
#pragma unroll
          for (int o = 0; o < 3; o++) po[r2][o] += __shfl_xor(po[r2][o], s, 64);
      if (lr == 0) {
#pragma unroll
        for (int r2 = 0; r2 < 4; r2++) {
          long grow = rowoff + bm0 + wr * 128 + i * 16 + kg * 4 + r2;
          float* p = outp + ((size_t)slice * NQVAL + grow) * 3;
          p[0] = po[r2][0];
          p[1] = po[r2][1];
          p[2] = po[r2][2];
        }
      }
    }
  } else {
    const int gq = (int)(bm0 >> 13);  // 8192 query rows per graph (256 | 8192)
    float bb[4], fm[4];
#pragma unroll
    for (int n = 0; n < 4; n++) {
      int col = bn0 + wc * 64 + n * 16 + lr;
      bb[n] = bias[col];
      fm[n] = (MODE == 1) ? field[gq * 512 + col] : 0.0f;
    }
#pragma unroll
    for (int i = 0; i < 8; i++)
#pragma unroll
      for (int n = 0; n < 4; n++) {
        int col = bn0 + wc * 64 + n * 16 + lr;
#pragma unroll
        for (int r2 = 0; r2 < 4; r2++) {
          long row = bm0 + wr * 128 + i * 16 + kg * 4 + r2;
          float v = acc[i][n][r2] + bb[n];
          v = (MODE == 1) ? v * fm[n] : fmaxf(v, 0.0f);
          C[row * 512 + col] = f2bf(v);
        }
      }
  }
}

extern "C" void kernel_launch(void* const* d_in, const int* in_sizes, int n_in,
                              void* d_out, int out_size, void* d_ws, size_t ws_size,
                              hipStream_t stream) {
  const float* known = (const float*)d_in[0];
  const float* nodes = (const float*)d_in[1];
  const int* esrc = (const int*)d_in[2];
  const int* edst = (const int*)d_in[3];
  const float* gc_w0 = (const float*)d_in[6];
  const float* gc_b0 = (const float*)d_in[7];
  const float* gc_w1 = (const float*)d_in[8];
  const float* gc_b1 = (const float*)d_in[9];
  const float* gc_w2 = (const float*)d_in[10];
  const float* gc_b2 = (const float*)d_in[11];
  const float* gc_wr = (const float*)d_in[12];
  const float* gc_br = (const float*)d_in[13];
  const float* wt1 = (const float*)d_in[14];
  const float* bt1 = (const float*)d_in[15];
  const float* wt2 = (const float*)d_in[16];
  const float* bt2 = (const float*)d_in[17];
  const float* wo1 = (const float*)d_in[18];
  const float* bo1 = (const float*)d_in[19];
  const float* wo2 = (const float*)d_in[20];
  const float* bo2 = (const float*)d_in[21];
  float* out = (float*)d_out;
  (void)in_sizes; (void)n_in; (void)out_size;

  char* ws = (char*)d_ws;
  size_t off_b = 0;
  auto alloc = [&](size_t n) -> void* {
    void* p = ws + off_b;
    off_b += (n + 255) & ~(size_t)255;
    return p;
  };
  u16* w1T   = (u16*)alloc(512 * 512 * 2);
  u16* w2T   = (u16*)alloc(512 * 512 * 2);
  u16* wt2T  = (u16*)alloc(512 * 512 * 2);
  u16* wo1T  = (u16*)alloc(512 * 512 * 2);
  int* cnt   = (int*)alloc(NKVAL * 4);
  int* off   = (int*)alloc((NKVAL + 1) * 4);
  int* cur   = (int*)alloc(NKVAL * 4);
  int* srcs  = (int*)alloc((size_t)EVAL * 4);
  float* m0     = (float*)alloc(NKVAL * 3 * 4);
  float* pooled = (float*)alloc(32 * 512 * 4);
  float* field  = (float*)alloc(32 * 512 * 4);
  u16* bufA = (u16*)alloc((size_t)NKVAL * 512 * 2);  // aliased as outpart in query phase
  u16* bufB = (u16*)alloc((size_t)NKVAL * 512 * 2);
  u16* bufC = (u16*)alloc((size_t)NKVAL * 512 * 2);
  float* outpart = (float*)bufA;  // 8 slices x NQ x 3 f32 = 25.2MB <= 32MB

  // chunking: PREFER 131072 rows (zc = 134MB, fully L3-resident -> MODE2 reads z
  // from L3 instead of HBM; r7's 268MB zc at nch=1 overflowed the 256MB L3)
  size_t rem = (ws_size > off_b) ? ws_size - off_b : 0;
  int chunk_rows = 32768;
  if ((size_t)131072 * 1024 <= rem) chunk_rows = 131072;
  else if ((size_t)65536 * 1024 <= rem) chunk_rows = 65536;
  u16* zc = (u16*)alloc((size_t)chunk_rows * 512 * 2);
  const int nch = NQVAL / chunk_rows;

  hipMemsetAsync(cnt, 0, NKVAL * 4, stream);
  hipMemsetAsync(cur, 0, NKVAL * 4, stream);
  hipMemsetAsync(pooled, 0, 32 * 512 * 4, stream);

  wcast4_k<<<dim3(8, 8, 4), 256, 0, stream>>>(gc_w1, gc_w2, wt2, wo1, w1T, w2T, wt2T, wo1T);

  degcnt_k<<<EVAL / 256, 256, 0, stream>>>(edst, cnt);
  scan_k<<<1, 1024, 0, stream>>>(cnt, off);
  scatter_k<<<EVAL / 256, 256, 0, stream>>>(esrc, edst, off, cur, srcs);
  agg0_csr<<<NKVAL / 256, 256, 0, stream>>>(off, srcs, known, m0);

  // h0 = relu((m0/deg) @ gc_w0 + b0)
  k3_dense<<<NKVAL * 64 / 256, 256, 0, stream>>>(m0, cnt, gc_w0, gc_b0, bufA, NKVAL);
  // m1 = segsum(h0[src])/deg  (CSR gather, XCD-local)
  agg_csr<<<NKVAL / 4, 256, 0, stream>>>(bufA, off, srcs, bufB);
  // h1 = relu(m1 @ W1 + b1)
  gemm_bt<0><<<dim3(2, NKVAL / 256), 512, 0, stream>>>(bufB, w1T, gc_b1, nullptr, nullptr, bufC, nullptr, 0,
                                                       nullptr, nullptr, nullptr);
  // m2
  agg_csr<<<NKVAL / 4, 256, 0, stream>>>(bufC, off, srcs, bufA);
  // h2
  gemm_bt<0><<<dim3(2, NKVAL / 256), 512, 0, stream>>>(bufA, w2T, gc_b2, nullptr, nullptr, bufB, nullptr, 0,
                                                       nullptr, nullptr, nullptr);
  pool_k<<<dim3(8, 32), 256, 0, stream>>>(bufB, pooled);
  field_k<<<64, 256, 0, stream>>>(pooled, gc_wr, gc_br, field);

  for (int ch = 0; ch < nch; ch++) {
    long rowoff = (long)ch * chunk_rows;
    // z = (relu(nodes@wt1+bt1) @ wt2 + bt2) * field[seg]   (trunk-1 fused into staging)
    gemm_bt<1><<<dim3(2, chunk_rows / 256), 512, 0, stream>>>(nullptr, wt2T, bt2,
                                                              field + (rowoff >> 13) * 512, nullptr, zc, nullptr, 0,
                                                              nodes + rowoff * 3, wt1, bt1);
    // partial[slice] = relu(z @ wo1 + bo1) @ wo2   (per 64-col slice, no atomics)
    gemm_bt<2><<<dim3(2, chunk_rows / 256), 512, 0, stream>>>(zc, wo1T, bo1, nullptr, wo2, nullptr,
                                                              outpart, rowoff, nullptr, nullptr, nullptr);
  }
  // out = sum of 8 slices + bo2
  out_reduce<<<NQVAL * 3 / 256, 256, 0, stream>>>(outpart, bo2, out);
}